// Round 2
// baseline (32630.487 us; speedup 1.0000x reference)
//
#include <hip/hip_runtime.h>
#include <math.h>

#define DM   512   // module dim
#define SP   1568  // 8*14*14 spatial
#define BATCH 32
#define NSTEP 12

__device__ __forceinline__ float eluf(float x) { return x > 0.f ? x : expf(x) - 1.f; }

// bf16 <-> fp32 (RNE)
__device__ __forceinline__ float b2f(ushort u) {
  union { float f; unsigned i; } v; v.i = ((unsigned)u) << 16; return v.f;
}
__device__ __forceinline__ ushort f2b(float f) {
  union { float f; unsigned i; } v; v.f = f;
  unsigned r = (v.i + 0x7FFFu + ((v.i >> 16) & 1u)) >> 16;
  return (ushort)r;
}
__device__ __forceinline__ float ldf(const float* p)  { return *p; }
__device__ __forceinline__ float ldf(const ushort* p) { return b2f(*p); }

// ---------------------------------------------------------------------------
// Implicit-GEMM conv3d (3x3x3 SAME) + bias + ELU. Output stored bf16.
// A = weights row-major [512, Cin*27]; B = gathered input [Cin*27, 1568] per b.
// trans=0: Y[b][co][s]  (channel-major, feeds conv2)
// trans=1: Y[b][s][co]  (know layout)
// ---------------------------------------------------------------------------
template <typename TX>
__global__ __launch_bounds__(256) void k_conv(
    const float* __restrict__ Wt, const TX* __restrict__ X,
    const float* __restrict__ bias, ushort* __restrict__ Y,
    int Cin, int trans)
{
  const int KK  = Cin * 27;
  const int b   = blockIdx.z;
  const int s0  = blockIdx.x * 64;
  const int co0 = blockIdx.y * 64;
  __shared__ float As[16][64];
  __shared__ float Bs[16][64];
  const int t  = threadIdx.x;
  const int tx = t & 15, ty = t >> 4;
  const int am = t & 63, ak4 = (t >> 6) * 4;
  const int bk = t >> 4, bn4 = (t & 15) * 4;
  float acc[4][4] = {{0.f}};

  for (int k0 = 0; k0 < KK; k0 += 16) {
    float4 av = *(const float4*)&Wt[(size_t)(co0 + am) * KK + k0 + ak4];
    As[ak4 + 0][am] = av.x; As[ak4 + 1][am] = av.y;
    As[ak4 + 2][am] = av.z; As[ak4 + 3][am] = av.w;
    {
      int k = k0 + bk;
      int ci = k / 27, tap = k - ci * 27;
      int kd = tap / 9, r9 = tap - kd * 9, kh = r9 / 3, kw = r9 - kh * 3;
      const TX* Xc = X + (size_t)(b * Cin + ci) * SP;
      float tmp[4];
#pragma unroll
      for (int i = 0; i < 4; i++) {
        int s = s0 + bn4 + i;
        float v = 0.f;
        if (s < SP) {
          int z = s / 196, r = s - z * 196, y = r / 14, x = r - y * 14;
          int zz = z + kd - 1, yy = y + kh - 1, xx = x + kw - 1;
          if ((unsigned)zz < 8u && (unsigned)yy < 14u && (unsigned)xx < 14u)
            v = ldf(&Xc[zz * 196 + yy * 14 + xx]);
        }
        tmp[i] = v;
      }
      *(float4*)&Bs[bk][bn4] = make_float4(tmp[0], tmp[1], tmp[2], tmp[3]);
    }
    __syncthreads();
#pragma unroll
    for (int kk = 0; kk < 16; kk++) {
      float a_[4], b_[4];
      *(float4*)a_ = *(const float4*)&As[kk][ty * 4];
      *(float4*)b_ = *(const float4*)&Bs[kk][tx * 4];
#pragma unroll
      for (int i = 0; i < 4; i++)
#pragma unroll
        for (int j = 0; j < 4; j++)
          acc[i][j] = fmaf(a_[i], b_[j], acc[i][j]);
    }
    __syncthreads();
  }

  if (!trans) {
#pragma unroll
    for (int i = 0; i < 4; i++) {
      int co = co0 + ty * 4 + i;
      float bi = bias[co];
      int s = s0 + tx * 4;
      if (s < SP) {  // SP%4==0: whole group valid or none
        ushort4 o;
        o.x = f2b(eluf(acc[i][0] + bi)); o.y = f2b(eluf(acc[i][1] + bi));
        o.z = f2b(eluf(acc[i][2] + bi)); o.w = f2b(eluf(acc[i][3] + bi));
        *(ushort4*)&Y[((size_t)b * DM + co) * SP + s] = o;
      }
    }
  } else {
#pragma unroll
    for (int j = 0; j < 4; j++) {
      int s = s0 + tx * 4 + j;
      if (s < SP) {
        int co = co0 + ty * 4;
        ushort4 o;
        o.x = f2b(eluf(acc[0][j] + bias[co + 0]));
        o.y = f2b(eluf(acc[1][j] + bias[co + 1]));
        o.z = f2b(eluf(acc[2][j] + bias[co + 2]));
        o.w = f2b(eluf(acc[3][j] + bias[co + 3]));
        *(ushort4*)&Y[((size_t)b * SP + s) * DM + co] = o;
      }
    }
  }
}

// ---------------------------------------------------------------------------
// Shared GEMM skeleton, K = N = 512. A is bf16.
// MODE 0: kproj = know @ Wk + bk            (M = 50176 flat)   -> bf16
// MODE 1: inter1[b] = elu(kproj[b] @ (mp[b,k]*Wcat[k,:]+Wcat[512+k,:]) + bcat) -> bf16
// MODE 2: rlpart[b][jt][s] = sum_{j in tile} elu((inter1[b]@Wcat2+bcat2)[s,j]*c[b,j])*raw[j] -> fp32
// ---------------------------------------------------------------------------
template <int MODE>
__global__ __launch_bounds__(256) void k_gemm(
    const ushort* __restrict__ A0, const float* __restrict__ Bm,
    const float* __restrict__ bias, const float* scale,
    const float* __restrict__ rvec, void* __restrict__ Cv)
{
  const int b  = blockIdx.z;
  const int n0 = blockIdx.y * 64;
  const int m0 = blockIdx.x * 64;
  const ushort* A = (MODE == 0) ? A0 : A0 + (size_t)b * SP * DM;
  __shared__ float As[16][64];
  __shared__ float Bs[16][64];
  __shared__ float red[64][17];
  const int t  = threadIdx.x;
  const int tx = t & 15, ty = t >> 4;
  const int am = t & 63, ak4 = (t >> 6) * 4;
  const int bk = t >> 4, bn4 = (t & 15) * 4;
  float acc[4][4] = {{0.f}};

  for (int k0 = 0; k0 < DM; k0 += 16) {
    int row = m0 + am;
    if (MODE == 0 || row < SP) {
      ushort4 av = *(const ushort4*)&A[(size_t)row * DM + k0 + ak4];
      As[ak4 + 0][am] = b2f(av.x); As[ak4 + 1][am] = b2f(av.y);
      As[ak4 + 2][am] = b2f(av.z); As[ak4 + 3][am] = b2f(av.w);
    } else {
      As[ak4 + 0][am] = 0.f; As[ak4 + 1][am] = 0.f;
      As[ak4 + 2][am] = 0.f; As[ak4 + 3][am] = 0.f;
    }

    float4 bv = *(const float4*)&Bm[(size_t)(k0 + bk) * DM + n0 + bn4];
    if (MODE == 1) {
      float4 b2 = *(const float4*)&Bm[(size_t)(DM + k0 + bk) * DM + n0 + bn4];
      float mpv = scale[b * DM + k0 + bk];
      bv.x = fmaf(mpv, bv.x, b2.x); bv.y = fmaf(mpv, bv.y, b2.y);
      bv.z = fmaf(mpv, bv.z, b2.z); bv.w = fmaf(mpv, bv.w, b2.w);
    }
    *(float4*)&Bs[bk][bn4] = bv;
    __syncthreads();
#pragma unroll
    for (int kk = 0; kk < 16; kk++) {
      float a_[4], b_[4];
      *(float4*)a_ = *(const float4*)&As[kk][ty * 4];
      *(float4*)b_ = *(const float4*)&Bs[kk][tx * 4];
#pragma unroll
      for (int i = 0; i < 4; i++)
#pragma unroll
        for (int j = 0; j < 4; j++)
          acc[i][j] = fmaf(a_[i], b_[j], acc[i][j]);
    }
    __syncthreads();
  }

  const int nn = n0 + tx * 4;
  if (MODE == 0) {
    ushort* C = (ushort*)Cv;
    float4 bb = *(const float4*)&bias[nn];
#pragma unroll
    for (int i = 0; i < 4; i++) {
      size_t row = (size_t)m0 + ty * 4 + i;
      ushort4 o;
      o.x = f2b(acc[i][0] + bb.x); o.y = f2b(acc[i][1] + bb.y);
      o.z = f2b(acc[i][2] + bb.z); o.w = f2b(acc[i][3] + bb.w);
      *(ushort4*)&C[row * DM + nn] = o;
    }
  } else if (MODE == 1) {
    ushort* C = (ushort*)Cv;
    float4 bb = *(const float4*)&bias[nn];
#pragma unroll
    for (int i = 0; i < 4; i++) {
      int row = m0 + ty * 4 + i;
      if (row < SP) {
        ushort4 o;
        o.x = f2b(eluf(acc[i][0] + bb.x)); o.y = f2b(eluf(acc[i][1] + bb.y));
        o.z = f2b(eluf(acc[i][2] + bb.z)); o.w = f2b(eluf(acc[i][3] + bb.w));
        *(ushort4*)&C[((size_t)b * SP + row) * DM + nn] = o;
      }
    }
  } else {
    float* C = (float*)Cv;
    float4 bb = *(const float4*)&bias[nn];
    float4 cv = *(const float4*)&scale[b * DM + nn];
    float4 rw = *(const float4*)&rvec[nn];
#pragma unroll
    for (int i = 0; i < 4; i++) {
      float p = 0.f;
      p += eluf((acc[i][0] + bb.x) * cv.x) * rw.x;
      p += eluf((acc[i][1] + bb.y) * cv.y) * rw.y;
      p += eluf((acc[i][2] + bb.z) * cv.z) * rw.z;
      p += eluf((acc[i][3] + bb.w) * cv.w) * rw.w;
      red[ty * 4 + i][tx] = p;
    }
    __syncthreads();
    if (t < 64) {
      int s = m0 + t;
      if (s < SP) {
        float sum = 0.f;
#pragma unroll
        for (int q = 0; q < 16; q++) sum += red[t][q];
        C[((size_t)b * 8 + blockIdx.y) * SP + s] = sum;
      }
    }
  }
}

// ---------------------------------------------------------------------------
// Control unit (one block per batch): q0=tanh([c,m]@Wci+bci), q=q0@Wu_i+bu_i,
// softmax over 80 concepts -> c_new; also mp = m@Wm+bm.
// ---------------------------------------------------------------------------
__global__ __launch_bounds__(256) void k_ctrl(
    const float* cin, const float* __restrict__ min_,
    const float* __restrict__ Wci, const float* __restrict__ bci,
    const float* __restrict__ Wu_i, const float* __restrict__ bu_i,
    const float* __restrict__ caw, const float* __restrict__ cab,
    const float* __restrict__ concepts,
    const float* __restrict__ Wm, const float* __restrict__ bm,
    float* cout, float* __restrict__ mpout)
{
  const int b = blockIdx.x, t = threadIdx.x;
  __shared__ float sc[512], sm[512], sq0[512], sqa[512], scl[80], red[256];
  sc[t] = cin[b * DM + t];       sc[t + 256] = cin[b * DM + t + 256];
  sm[t] = min_[b * DM + t];      sm[t + 256] = min_[b * DM + t + 256];
  __syncthreads();
#pragma unroll
  for (int h = 0; h < 2; h++) {
    int d = t + h * 256;
    float a = bci[d];
    for (int k = 0; k < 512; k++) a = fmaf(sc[k], Wci[k * DM + d], a);
    for (int k = 0; k < 512; k++) a = fmaf(sm[k], Wci[(512 + k) * DM + d], a);
    sq0[d] = tanhf(a);
    float mpa = bm[d];
    for (int k = 0; k < 512; k++) mpa = fmaf(sm[k], Wm[k * DM + d], mpa);
    mpout[b * DM + d] = mpa;
  }
  __syncthreads();
#pragma unroll
  for (int h = 0; h < 2; h++) {
    int d = t + h * 256;
    float a = bu_i[d];
    for (int k = 0; k < 512; k++) a = fmaf(sq0[k], Wu_i[k * DM + d], a);
    sqa[d] = a * caw[d];
  }
  __syncthreads();
  float myl = -INFINITY;
  if (t < 80) {
    float a = cab[0];
    for (int d = 0; d < 512; d++) a = fmaf(sqa[d], concepts[t * DM + d], a);
    scl[t] = a; myl = a;
  }
  red[t] = myl; __syncthreads();
  for (int s = 128; s > 0; s >>= 1) { if (t < s) red[t] = fmaxf(red[t], red[t + s]); __syncthreads(); }
  float mx = red[0]; __syncthreads();
  float e = 0.f;
  if (t < 80) { e = expf(scl[t] - mx); }
  red[t] = e; __syncthreads();
  for (int s = 128; s > 0; s >>= 1) { if (t < s) red[t] += red[t + s]; __syncthreads(); }
  float inv = 1.f / red[0]; __syncthreads();
  if (t < 80) scl[t] = e * inv;
  __syncthreads();
#pragma unroll
  for (int h = 0; h < 2; h++) {
    int d = t + h * 256;
    float a = 0.f;
    for (int l = 0; l < 80; l++) a = fmaf(scl[l], concepts[l * DM + d], a);
    cout[b * DM + d] = a;
  }
}

// rl = sum(rlpart) + rb; softmax over 1568 -> rattn
__global__ __launch_bounds__(256) void k_softmax_read(
    const float* __restrict__ rlpart, const float* __restrict__ rb,
    float* __restrict__ rattn)
{
  const int b = blockIdx.x, t = threadIdx.x;
  __shared__ float red[256];
  const float rb0 = rb[0];
  float vals[7]; float vmax = -INFINITY;
#pragma unroll
  for (int q = 0; q < 7; q++) {
    int s = t + q * 256;
    float v = -INFINITY;
    if (s < SP) {
      v = rb0;
      for (int c = 0; c < 8; c++) v += rlpart[((size_t)b * 8 + c) * SP + s];
    }
    vals[q] = v; vmax = fmaxf(vmax, v);
  }
  red[t] = vmax; __syncthreads();
  for (int s = 128; s > 0; s >>= 1) { if (t < s) red[t] = fmaxf(red[t], red[t + s]); __syncthreads(); }
  float mx = red[0]; __syncthreads();
  float lsum = 0.f;
#pragma unroll
  for (int q = 0; q < 7; q++) {
    int s = t + q * 256;
    float ee = (s < SP) ? expf(vals[q] - mx) : 0.f;
    vals[q] = ee; lsum += ee;
  }
  red[t] = lsum; __syncthreads();
  for (int s = 128; s > 0; s >>= 1) { if (t < s) red[t] += red[t + s]; __syncthreads(); }
  float inv = 1.f / red[0];
#pragma unroll
  for (int q = 0; q < 7; q++) {
    int s = t + q * 256;
    if (s < SP) rattn[b * SP + s] = vals[q] * inv;
  }
}

// infopart[b][chunk][d] = sum_{s in chunk} rattn[b,s] * know[b,s,d]   (know bf16)
__global__ __launch_bounds__(256) void k_infopart(
    const float* __restrict__ rattn, const ushort* __restrict__ know,
    float* __restrict__ ipart)
{
  const int b = blockIdx.x, c = blockIdx.y, t = threadIdx.x;
  float a0 = 0.f, a1 = 0.f;
  for (int s = c * 196; s < (c + 1) * 196; s++) {
    float r = rattn[b * SP + s];
    const ushort* kr = know + ((size_t)b * SP + s) * DM;
    a0 = fmaf(r, b2f(kr[t]), a0);
    a1 = fmaf(r, b2f(kr[t + 256]), a1);
  }
  ipart[((size_t)b * 8 + c) * DM + t] = a0;
  ipart[((size_t)b * 8 + c) * DM + t + 256] = a1;
}

// m_new = [m_old, info] @ Wwrite + bwrite
__global__ __launch_bounds__(256) void k_write(
    const float* __restrict__ mold, const float* __restrict__ ipart,
    const float* __restrict__ Ww, const float* __restrict__ bw,
    float* __restrict__ mnew)
{
  const int b = blockIdx.x, half = blockIdx.y, t = threadIdx.x;
  __shared__ float smo[512], sinfo[512];
  for (int k = t; k < 512; k += 256) {
    smo[k] = mold[b * DM + k];
    float s = 0.f;
    for (int c = 0; c < 8; c++) s += ipart[((size_t)b * 8 + c) * DM + k];
    sinfo[k] = s;
  }
  __syncthreads();
  int d = half * 256 + t;
  float a = bw[d];
  for (int k = 0; k < 512; k++) a = fmaf(smo[k], Ww[k * DM + d], a);
  for (int k = 0; k < 512; k++) a = fmaf(sinfo[k], Ww[(512 + k) * DM + d], a);
  mnew[b * DM + d] = a;
}

__global__ void k_init(const float* __restrict__ initc, const float* __restrict__ initm,
                       float* __restrict__ cbuf, float* __restrict__ mbuf)
{
  const int b = blockIdx.x, t = threadIdx.x;
  cbuf[b * DM + t] = initc[t];
  mbuf[b * DM + t] = initm[t];
}

// mw[b,p] = (m @ Wproj + bproj)[p] * out_attn_w[p]
__global__ void k_mpo(const float* __restrict__ m, const float* __restrict__ Wproj,
                      const float* __restrict__ bproj, const float* __restrict__ ow,
                      float* __restrict__ mw)
{
  const int b = blockIdx.x, t = threadIdx.x;
  __shared__ float smem[512];
  for (int k = t; k < 512; k += 320) smem[k] = m[b * DM + k];
  __syncthreads();
  if (t < 300) {
    float a = bproj[t];
    for (int k = 0; k < 512; k++) a = fmaf(smem[k], Wproj[k * 300 + t], a);
    mw[b * 300 + t] = a * ow[t];
  }
}

__global__ void k_logits(const float* __restrict__ mw, const float* __restrict__ labels,
                         const float* __restrict__ ob, float* __restrict__ logits)
{
  const int b = blockIdx.x, t = threadIdx.x;
  const int a = blockIdx.y * 256 + t;
  __shared__ float smw[300];
  for (int p = t; p < 300; p += 256) smw[p] = mw[b * 300 + p];
  __syncthreads();
  if (a < 1000) {
    float acc = ob[0];
    for (int p = 0; p < 300; p++) acc = fmaf(smw[p], labels[a * 300 + p], acc);
    logits[b * 1000 + a] = acc;
  }
}

__global__ void k_softmax_out(const float* __restrict__ logits, float* __restrict__ out)
{
  const int b = blockIdx.x, t = threadIdx.x;
  __shared__ float red[256];
  float v[4]; float vmax = -INFINITY;
#pragma unroll
  for (int q = 0; q < 4; q++) {
    int a = t + q * 256;
    v[q] = (a < 1000) ? logits[b * 1000 + a] : -INFINITY;
    vmax = fmaxf(vmax, v[q]);
  }
  red[t] = vmax; __syncthreads();
  for (int s = 128; s > 0; s >>= 1) { if (t < s) red[t] = fmaxf(red[t], red[t + s]); __syncthreads(); }
  float mx = red[0]; __syncthreads();
  float lsum = 0.f;
#pragma unroll
  for (int q = 0; q < 4; q++) {
    int a = t + q * 256;
    v[q] = (a < 1000) ? expf(v[q] - mx) : 0.f;
    lsum += v[q];
  }
  red[t] = lsum; __syncthreads();
  for (int s = 128; s > 0; s >>= 1) { if (t < s) red[t] += red[t + s]; __syncthreads(); }
  float inv = 1.f / red[0];
#pragma unroll
  for (int q = 0; q < 4; q++) {
    int a = t + q * 256;
    if (a < 1000) out[b * 1000 + a] = v[q] * inv;
  }
}

// ---------------------------------------------------------------------------
extern "C" void kernel_launch(void* const* d_in, const int* in_sizes, int n_in,
                              void* d_out, int out_size, void* d_ws, size_t ws_size,
                              hipStream_t stream)
{
  const float* image    = (const float*)d_in[0];
  const float* concepts = (const float*)d_in[1];
  const float* conv1_w  = (const float*)d_in[2];
  const float* conv1_b  = (const float*)d_in[3];
  const float* conv2_w  = (const float*)d_in[4];
  const float* conv2_b  = (const float*)d_in[5];
  const float* Wci      = (const float*)d_in[6];
  const float* bci      = (const float*)d_in[7];
  const float* Wu       = (const float*)d_in[8];
  const float* bu       = (const float*)d_in[9];
  const float* caw      = (const float*)d_in[10];
  const float* cab      = (const float*)d_in[11];
  const float* Wk       = (const float*)d_in[12];
  const float* bk       = (const float*)d_in[13];
  const float* Wm       = (const float*)d_in[14];
  const float* bm       = (const float*)d_in[15];
  const float* Wcat     = (const float*)d_in[16];
  const float* bcat     = (const float*)d_in[17];
  const float* Wcat2    = (const float*)d_in[18];
  const float* bcat2    = (const float*)d_in[19];
  const float* raw      = (const float*)d_in[20];
  const float* rab      = (const float*)d_in[21];
  const float* Wwrite   = (const float*)d_in[22];
  const float* bwrite   = (const float*)d_in[23];
  const float* initc    = (const float*)d_in[24];
  const float* initm    = (const float*)d_in[25];
  const float* Wproj    = (const float*)d_in[26];
  const float* bproj    = (const float*)d_in[27];
  const float* oaw      = (const float*)d_in[28];
  const float* oab      = (const float*)d_in[29];
  const float* labels   = (const float*)d_in[30];

  char* ws = (char*)d_ws;
  size_t off = 0;
  auto allocB = [&](size_t bytes) {
    void* p = ws + off; off += (bytes + 255) & ~(size_t)255; return p;
  };
  const size_t BIG = (size_t)BATCH * SP * DM;  // 25,690,112 elems
  ushort* convbuf = (ushort*)allocB(BIG * 2);  // conv1 out (bf16) -> inter1
  ushort* know    = (ushort*)allocB(BIG * 2);  // [b][s][d] bf16
  ushort* kproj   = (ushort*)allocB(BIG * 2);  // [b][s][d] bf16
  float* rlpart = (float*)allocB((size_t)BATCH * 8 * SP * 4);
  float* rattn  = (float*)allocB((size_t)BATCH * SP * 4);
  float* ipart  = (float*)allocB((size_t)BATCH * 8 * DM * 4);
  float* cbuf   = (float*)allocB(BATCH * DM * 4);
  float* mbufA  = (float*)allocB(BATCH * DM * 4);
  float* mbufB  = (float*)allocB(BATCH * DM * 4);
  float* mp     = (float*)allocB(BATCH * DM * 4);
  float* mw     = (float*)allocB(BATCH * 300 * 4);
  float* logits = (float*)allocB(BATCH * 1000 * 4);

  // Workspace guard: fail gracefully (absmax mismatch) instead of corrupting
  // memory if the harness workspace is smaller than required (~157 MB).
  if (off > ws_size) return;

  dim3 gconv(25, 8, BATCH);
  k_conv<float ><<<gconv, 256, 0, stream>>>(conv1_w, image,   conv1_b, convbuf, 256, 0);
  k_conv<ushort><<<gconv, 256, 0, stream>>>(conv2_w, convbuf, conv2_b, know,    512, 1);
  k_gemm<0><<<dim3(784, 8, 1), 256, 0, stream>>>(know, Wk, bk, nullptr, nullptr, kproj);
  k_init<<<BATCH, DM, 0, stream>>>(initc, initm, cbuf, mbufA);

  float* mc = mbufA; float* mn = mbufB;
  for (int i = 0; i < NSTEP; i++) {
    k_ctrl<<<BATCH, 256, 0, stream>>>(cbuf, mc, Wci, bci,
                                      Wu + (size_t)i * DM * DM, bu + i * DM,
                                      caw, cab, concepts, Wm, bm, cbuf, mp);
    k_gemm<1><<<dim3(25, 8, BATCH), 256, 0, stream>>>(kproj, Wcat, bcat, mp, nullptr, convbuf);
    k_gemm<2><<<dim3(25, 8, BATCH), 256, 0, stream>>>(convbuf, Wcat2, bcat2, cbuf, raw, rlpart);
    k_softmax_read<<<BATCH, 256, 0, stream>>>(rlpart, rab, rattn);
    k_infopart<<<dim3(BATCH, 8), 256, 0, stream>>>(rattn, know, ipart);
    k_write<<<dim3(BATCH, 2), 256, 0, stream>>>(mc, ipart, Wwrite, bwrite, mn);
    float* tswap = mc; mc = mn; mn = tswap;
  }

  k_mpo<<<BATCH, 320, 0, stream>>>(mc, Wproj, bproj, oaw, mw);
  k_logits<<<dim3(BATCH, 4), 256, 0, stream>>>(mw, labels, oab, logits);
  k_softmax_out<<<BATCH, 256, 0, stream>>>(logits, (float*)d_out);

  (void)in_sizes; (void)n_in; (void)out_size;
}

// Round 3
// 9509.814 us; speedup vs baseline: 3.4312x; 3.4312x over previous
//
#include <hip/hip_runtime.h>
#include <math.h>

#define DM    512
#define SP    1568   // 8*14*14
#define BATCH 32
#define NSTEP 12
#define NPAD  2048   // padded spatial (8*16*16)
#define CPAD  2560   // padded per-channel volume (10*16*16)
#define LDT   40     // LDS tile row stride (bf16 elems), pad vs 32

typedef short s16x8 __attribute__((ext_vector_type(8)));
typedef float f32x4 __attribute__((ext_vector_type(4)));

__device__ __forceinline__ float eluf(float x) { return x > 0.f ? x : expf(x) - 1.f; }
__device__ __forceinline__ float b2f(ushort u) {
  union { float f; unsigned i; } v; v.i = ((unsigned)u) << 16; return v.f;
}
__device__ __forceinline__ ushort f2b(float f) {
  union { float f; unsigned i; } v; v.f = f;
  unsigned r = (v.i + 0x7FFFu + ((v.i >> 16) & 1u)) >> 16;
  return (ushort)r;
}

// ---------------------------------------------------------------------------
__global__ void k_zero(uint4* __restrict__ p, long n16) {
  long stride = (long)gridDim.x * blockDim.x;
  for (long i = (long)blockIdx.x * blockDim.x + threadIdx.x; i < n16; i += stride)
    p[i] = make_uint4(0, 0, 0, 0);
}

// image [32][256][1568] fp32 -> padded bf16 [32*256][2560] (interior only)
__global__ void k_padimg(const float* __restrict__ img, ushort* __restrict__ xp) {
  int idx = blockIdx.x * 256 + threadIdx.x;   // < 32*256*1568
  int s = idx % SP; int bc = idx / SP;
  int z = s / 196, r = s - z * 196, y = r / 14, x = r - y * 14;
  xp[(size_t)bc * CPAD + (z + 1) * 256 + (y + 1) * 16 + (x + 1)] = f2b(img[idx]);
}

// conv weights [co][ci][27] fp32 -> tap-major bf16 [co][tap*CIN+ci]
template <int CIN>
__global__ void k_cvtw(const float* __restrict__ w, ushort* __restrict__ o) {
  int idx = blockIdx.x * 256 + threadIdx.x;   // < 512*27*CIN
  const int KK = 27 * CIN;
  int co = idx / KK; int rem = idx - co * KK;
  int tap = rem / CIN; int ci = rem - tap * CIN;
  o[idx] = f2b(w[((size_t)co * CIN + ci) * 27 + tap]);
}

// [512][512] fp32 -> transposed bf16 [n][k]
__global__ void k_cvtT(const float* __restrict__ w, ushort* __restrict__ o) {
  int idx = blockIdx.x * 256 + threadIdx.x;   // < 512*512
  int n = idx >> 9, k = idx & 511;
  o[idx] = f2b(w[(size_t)k * 512 + n]);
}

// ---------------------------------------------------------------------------
// MFMA conv3d: implicit GEMM, M=co(512), N=s_pad(2048), K=27*CIN (tap-major).
// ISCONV1: store to padded layout (bf16, +ELU+bias); else store know [b][s][d].
// ---------------------------------------------------------------------------
template <int CIN, int ISCONV1>
__global__ __launch_bounds__(256) void k_convm(
    const ushort* __restrict__ W, const ushort* __restrict__ Xp,
    const float* __restrict__ bias, ushort* __restrict__ Y)
{
  const int KK = CIN * 27;
  const int b  = blockIdx.z;
  const int n0 = blockIdx.x * 128;
  const int m0 = blockIdx.y * 128;
  __shared__ __align__(16) ushort As[128 * LDT];
  __shared__ __align__(16) ushort Bs[128 * LDT];
  const int t = threadIdx.x;
  const int lane = t & 63, wid = t >> 6;
  const int wm = (wid >> 1) * 64, wn = (wid & 1) * 64;
  const int l15 = lane & 15, quad = lane >> 4;
  f32x4 acc[4][4];
#pragma unroll
  for (int i = 0; i < 4; i++)
#pragma unroll
    for (int j = 0; j < 4; j++) acc[i][j] = (f32x4){0.f, 0.f, 0.f, 0.f};

  for (int k0 = 0; k0 < KK; k0 += 32) {
#pragma unroll
    for (int i = 0; i < 2; i++) {          // A tile: 128co x 32k, b128 loads
      int f = t + i * 256;
      int row = f >> 2, ko = (f & 3) * 8;
      uint4 v = *(const uint4*)&W[(size_t)(m0 + row) * KK + k0 + ko];
      *(uint4*)&As[row * LDT + ko] = v;
    }
    {                                       // B tile: fixed tap, contiguous run
      int tap = k0 / CIN, ci0 = k0 - tap * CIN;
      int dz = tap / 9, rr = tap - dz * 9, dy = rr / 3, dx = rr - dy * 3;
      int tofs = dz * 256 + dy * 16 + dx;
      int kk = t & 31, ns = (t >> 5) * 16;
      const ushort* src = Xp + ((size_t)b * CIN + ci0 + kk) * CPAD + tofs + n0 + ns;
#pragma unroll
      for (int e = 0; e < 16; e++) Bs[(ns + e) * LDT + kk] = src[e];
    }
    __syncthreads();
    s16x8 af[4], bfr[4];
#pragma unroll
    for (int i = 0; i < 4; i++)
      af[i] = *(const s16x8*)&As[(wm + i * 16 + l15) * LDT + quad * 8];
#pragma unroll
    for (int j = 0; j < 4; j++)
      bfr[j] = *(const s16x8*)&Bs[(wn + j * 16 + l15) * LDT + quad * 8];
#pragma unroll
    for (int i = 0; i < 4; i++)
#pragma unroll
      for (int j = 0; j < 4; j++)
        acc[i][j] = __builtin_amdgcn_mfma_f32_16x16x32_bf16(af[i], bfr[j], acc[i][j], 0, 0, 0);
    __syncthreads();
  }

#pragma unroll
  for (int i = 0; i < 4; i++) {
    int cob = m0 + wm + i * 16 + quad * 4;
    float4 bb = *(const float4*)&bias[cob];
#pragma unroll
    for (int j = 0; j < 4; j++) {
      int n = n0 + wn + j * 16 + l15;
      int z = n >> 8, y = (n >> 4) & 15, x = n & 15;
      if (y < 14 && x < 14) {
        if (ISCONV1) {
          size_t base = ((size_t)b * 512 + cob) * CPAD + (z + 1) * 256 + (y + 1) * 16 + (x + 1);
          Y[base           ] = f2b(eluf(acc[i][j][0] + bb.x));
          Y[base + CPAD    ] = f2b(eluf(acc[i][j][1] + bb.y));
          Y[base + 2 * CPAD] = f2b(eluf(acc[i][j][2] + bb.z));
          Y[base + 3 * CPAD] = f2b(eluf(acc[i][j][3] + bb.w));
        } else {
          int s = z * 196 + y * 14 + x;
          ushort4 o;
          o.x = f2b(eluf(acc[i][j][0] + bb.x));
          o.y = f2b(eluf(acc[i][j][1] + bb.y));
          o.z = f2b(eluf(acc[i][j][2] + bb.z));
          o.w = f2b(eluf(acc[i][j][3] + bb.w));
          *(ushort4*)&Y[((size_t)b * SP + s) * DM + cob] = o;
        }
      }
    }
  }
}

// ---------------------------------------------------------------------------
// MFMA GEMM: M = s (1568, masked), N = 512, K = 512. A bf16 [s][k], Bt bf16 [n][k].
// MODE 0: kproj = A@B + bias                 -> bf16
// MODE 1: inter1 = elu(A@Beff[bq] + bias)    -> bf16
// MODE 2: rlpart = sum_n elu((A@B+bias)*c)*raw  -> fp32, per n-tile
// ---------------------------------------------------------------------------
template <int MODE>
__global__ __launch_bounds__(256) void k_gemmm(
    const ushort* __restrict__ A0, const ushort* __restrict__ Bt0,
    const float* __restrict__ bias, const float* __restrict__ scale,
    const float* __restrict__ rvec, void* __restrict__ Cv, int bbase)
{
  const int bq = blockIdx.z, breal = bbase + bq;
  const int m0 = blockIdx.x * 128;
  const int n0 = blockIdx.y * 128;
  const ushort* A  = A0 + (size_t)bq * SP * DM;
  const ushort* Bt = (MODE == 1) ? Bt0 + (size_t)bq * DM * DM : Bt0;
  __shared__ __align__(16) ushort As[128 * LDT];
  __shared__ __align__(16) ushort Bs[128 * LDT];
  const int t = threadIdx.x;
  const int lane = t & 63, wid = t >> 6;
  const int wm = (wid >> 1) * 64, wn = (wid & 1) * 64;
  const int l15 = lane & 15, quad = lane >> 4;
  f32x4 acc[4][4];
#pragma unroll
  for (int i = 0; i < 4; i++)
#pragma unroll
    for (int j = 0; j < 4; j++) acc[i][j] = (f32x4){0.f, 0.f, 0.f, 0.f};

  for (int k0 = 0; k0 < DM; k0 += 32) {
#pragma unroll
    for (int i = 0; i < 2; i++) {
      int f = t + i * 256;
      int row = f >> 2, ko = (f & 3) * 8;
      int mg = m0 + row;
      uint4 v = make_uint4(0, 0, 0, 0);
      if (mg < SP) v = *(const uint4*)&A[(size_t)mg * DM + k0 + ko];
      *(uint4*)&As[row * LDT + ko] = v;
      uint4 w = *(const uint4*)&Bt[(size_t)(n0 + row) * DM + k0 + ko];
      *(uint4*)&Bs[row * LDT + ko] = w;
    }
    __syncthreads();
    s16x8 af[4], bfr[4];
#pragma unroll
    for (int i = 0; i < 4; i++)
      af[i] = *(const s16x8*)&As[(wm + i * 16 + l15) * LDT + quad * 8];
#pragma unroll
    for (int j = 0; j < 4; j++)
      bfr[j] = *(const s16x8*)&Bs[(wn + j * 16 + l15) * LDT + quad * 8];
#pragma unroll
    for (int i = 0; i < 4; i++)
#pragma unroll
      for (int j = 0; j < 4; j++)
        acc[i][j] = __builtin_amdgcn_mfma_f32_16x16x32_bf16(af[i], bfr[j], acc[i][j], 0, 0, 0);
    __syncthreads();
  }

  if constexpr (MODE <= 1) {
    ushort* C = (ushort*)Cv + (size_t)bq * SP * DM;
#pragma unroll
    for (int j = 0; j < 4; j++) {
      int n = n0 + wn + j * 16 + l15;
      float bb = bias[n];
#pragma unroll
      for (int i = 0; i < 4; i++) {
        int mb = m0 + wm + i * 16 + quad * 4;
#pragma unroll
        for (int r = 0; r < 4; r++) {
          int m = mb + r;
          if (m < SP) {
            float v = acc[i][j][r] + bb;
            if (MODE == 1) v = eluf(v);
            C[(size_t)m * DM + n] = f2b(v);
          }
        }
      }
    }
  } else {
    __shared__ float red[128][33];
    float* C = (float*)Cv;
#pragma unroll
    for (int i = 0; i < 4; i++) {
#pragma unroll
      for (int r = 0; r < 4; r++) {
        float p = 0.f;
#pragma unroll
        for (int j = 0; j < 4; j++) {
          int n = n0 + wn + j * 16 + l15;
          p += eluf((acc[i][j][r] + bias[n]) * scale[(size_t)breal * DM + n]) * rvec[n];
        }
        red[wm + i * 16 + quad * 4 + r][(wid & 1) * 16 + l15] = p;
      }
    }
    __syncthreads();
    if (t < 128) {
      int m = m0 + t;
      float s = 0.f;
#pragma unroll
      for (int q = 0; q < 32; q++) s += red[t][q];
      if (m < SP) C[((size_t)breal * 4 + blockIdx.y) * SP + m] = s;
    }
  }
}

// ---------------------------------------------------------------------------
// Per-step fold: Beff_t[bq][n][k] = bf16(mp[b][k]*Wcat[k][n] + Wcat[512+k][n])
// ---------------------------------------------------------------------------
__global__ __launch_bounds__(256) void k_prefold(
    const float* __restrict__ Wcat, const float* __restrict__ mp,
    ushort* __restrict__ Bf, int bbase)
{
  const int k0 = blockIdx.x * 64, n0 = blockIdx.y * 64;
  __shared__ float S1[64][68], S2[64][68];
  const int t = threadIdx.x;
#pragma unroll
  for (int i = 0; i < 4; i++) {
    int f = t + i * 256;
    int kk = f >> 4, nn = (f & 15) * 4;
    float4 a = *(const float4*)&Wcat[(size_t)(k0 + kk) * DM + n0 + nn];
    float4 c = *(const float4*)&Wcat[(size_t)(DM + k0 + kk) * DM + n0 + nn];
    *(float4*)&S1[kk][nn] = a;
    *(float4*)&S2[kk][nn] = c;
  }
  __syncthreads();
  const int n = t >> 2, kseg = (t & 3) * 16;
  for (int bq = 0; bq < 8; bq++) {
    const float* mpb = mp + (size_t)(bbase + bq) * DM + k0 + kseg;
    ushort* out = Bf + ((size_t)bq * DM + n0 + n) * DM + k0 + kseg;
#pragma unroll
    for (int g = 0; g < 4; g++) {
      ushort4 o;
      o.x = f2b(mpb[g * 4 + 0] * S1[kseg + g * 4 + 0][n] + S2[kseg + g * 4 + 0][n]);
      o.y = f2b(mpb[g * 4 + 1] * S1[kseg + g * 4 + 1][n] + S2[kseg + g * 4 + 1][n]);
      o.z = f2b(mpb[g * 4 + 2] * S1[kseg + g * 4 + 2][n] + S2[kseg + g * 4 + 2][n]);
      o.w = f2b(mpb[g * 4 + 3] * S1[kseg + g * 4 + 3][n] + S2[kseg + g * 4 + 3][n]);
      *(ushort4*)&out[g * 4] = o;
    }
  }
}

// ---------------------------------------------------------------------------
// Small fused per-step kernels (fp32)
// ---------------------------------------------------------------------------
__global__ __launch_bounds__(256) void k_ctrl(
    const float* cin, const float* __restrict__ min_,
    const float* __restrict__ Wci, const float* __restrict__ bci,
    const float* __restrict__ Wu_i, const float* __restrict__ bu_i,
    const float* __restrict__ caw, const float* __restrict__ cab,
    const float* __restrict__ concepts,
    const float* __restrict__ Wm, const float* __restrict__ bm,
    float* cout, float* __restrict__ mpout)
{
  const int b = blockIdx.x, t = threadIdx.x;
  __shared__ float sc[512], sm[512], sq0[512], sqa[512], scl[80], red[256];
  sc[t] = cin[b * DM + t];       sc[t + 256] = cin[b * DM + t + 256];
  sm[t] = min_[b * DM + t];      sm[t + 256] = min_[b * DM + t + 256];
  __syncthreads();
#pragma unroll
  for (int h = 0; h < 2; h++) {
    int d = t + h * 256;
    float a = bci[d];
    for (int k = 0; k < 512; k++) a = fmaf(sc[k], Wci[k * DM + d], a);
    for (int k = 0; k < 512; k++) a = fmaf(sm[k], Wci[(512 + k) * DM + d], a);
    sq0[d] = tanhf(a);
    float mpa = bm[d];
    for (int k = 0; k < 512; k++) mpa = fmaf(sm[k], Wm[k * DM + d], mpa);
    mpout[b * DM + d] = mpa;
  }
  __syncthreads();
#pragma unroll
  for (int h = 0; h < 2; h++) {
    int d = t + h * 256;
    float a = bu_i[d];
    for (int k = 0; k < 512; k++) a = fmaf(sq0[k], Wu_i[k * DM + d], a);
    sqa[d] = a * caw[d];
  }
  __syncthreads();
  float myl = -INFINITY;
  if (t < 80) {
    float a = cab[0];
    for (int d = 0; d < 512; d++) a = fmaf(sqa[d], concepts[t * DM + d], a);
    scl[t] = a; myl = a;
  }
  red[t] = myl; __syncthreads();
  for (int s = 128; s > 0; s >>= 1) { if (t < s) red[t] = fmaxf(red[t], red[t + s]); __syncthreads(); }
  float mx = red[0]; __syncthreads();
  float e = 0.f;
  if (t < 80) e = expf(scl[t] - mx);
  red[t] = e; __syncthreads();
  for (int s = 128; s > 0; s >>= 1) { if (t < s) red[t] += red[t + s]; __syncthreads(); }
  float inv = 1.f / red[0]; __syncthreads();
  if (t < 80) scl[t] = e * inv;
  __syncthreads();
#pragma unroll
  for (int h = 0; h < 2; h++) {
    int d = t + h * 256;
    float a = 0.f;
    for (int l = 0; l < 80; l++) a = fmaf(scl[l], concepts[l * DM + d], a);
    cout[b * DM + d] = a;
  }
}

__global__ __launch_bounds__(256) void k_softmax_read(
    const float* __restrict__ rlpart, const float* __restrict__ rb,
    float* __restrict__ rattn)
{
  const int b = blockIdx.x, t = threadIdx.x;
  __shared__ float red[256];
  const float rb0 = rb[0];
  float vals[7]; float vmax = -INFINITY;
#pragma unroll
  for (int q = 0; q < 7; q++) {
    int s = t + q * 256;
    float v = -INFINITY;
    if (s < SP) {
      v = rb0;
      for (int c = 0; c < 4; c++) v += rlpart[((size_t)b * 4 + c) * SP + s];
    }
    vals[q] = v; vmax = fmaxf(vmax, v);
  }
  red[t] = vmax; __syncthreads();
  for (int s = 128; s > 0; s >>= 1) { if (t < s) red[t] = fmaxf(red[t], red[t + s]); __syncthreads(); }
  float mx = red[0]; __syncthreads();
  float lsum = 0.f;
#pragma unroll
  for (int q = 0; q < 7; q++) {
    int s = t + q * 256;
    float ee = (s < SP) ? expf(vals[q] - mx) : 0.f;
    vals[q] = ee; lsum += ee;
  }
  red[t] = lsum; __syncthreads();
  for (int s = 128; s > 0; s >>= 1) { if (t < s) red[t] += red[t + s]; __syncthreads(); }
  float inv = 1.f / red[0];
#pragma unroll
  for (int q = 0; q < 7; q++) {
    int s = t + q * 256;
    if (s < SP) rattn[b * SP + s] = vals[q] * inv;
  }
}

__global__ __launch_bounds__(256) void k_infopart(
    const float* __restrict__ rattn, const ushort* __restrict__ know,
    float* __restrict__ ipart)
{
  const int b = blockIdx.x, c = blockIdx.y, t = threadIdx.x;
  float a0 = 0.f, a1 = 0.f;
  for (int s = c * 196; s < (c + 1) * 196; s++) {
    float r = rattn[b * SP + s];
    const ushort* kr = know + ((size_t)b * SP + s) * DM;
    a0 = fmaf(r, b2f(kr[t]), a0);
    a1 = fmaf(r, b2f(kr[t + 256]), a1);
  }
  ipart[((size_t)b * 8 + c) * DM + t] = a0;
  ipart[((size_t)b * 8 + c) * DM + t + 256] = a1;
}

__global__ __launch_bounds__(256) void k_write(
    const float* __restrict__ mold, const float* __restrict__ ipart,
    const float* __restrict__ Ww, const float* __restrict__ bw,
    float* __restrict__ mnew)
{
  const int b = blockIdx.x, half = blockIdx.y, t = threadIdx.x;
  __shared__ float smo[512], sinfo[512];
  for (int k = t; k < 512; k += 256) {
    smo[k] = mold[b * DM + k];
    float s = 0.f;
    for (int c = 0; c < 8; c++) s += ipart[((size_t)b * 8 + c) * DM + k];
    sinfo[k] = s;
  }
  __syncthreads();
  int d = half * 256 + t;
  float a = bw[d];
  for (int k = 0; k < 512; k++) a = fmaf(smo[k], Ww[k * DM + d], a);
  for (int k = 0; k < 512; k++) a = fmaf(sinfo[k], Ww[(512 + k) * DM + d], a);
  mnew[b * DM + d] = a;
}

__global__ void k_init(const float* __restrict__ initc, const float* __restrict__ initm,
                       float* __restrict__ cbuf, float* __restrict__ mbuf)
{
  const int b = blockIdx.x, t = threadIdx.x;
  cbuf[b * DM + t] = initc[t];
  mbuf[b * DM + t] = initm[t];
}

__global__ void k_mpo(const float* __restrict__ m, const float* __restrict__ Wproj,
                      const float* __restrict__ bproj, const float* __restrict__ ow,
                      float* __restrict__ mw)
{
  const int b = blockIdx.x, t = threadIdx.x;
  __shared__ float smem[512];
  for (int k = t; k < 512; k += 320) smem[k] = m[b * DM + k];
  __syncthreads();
  if (t < 300) {
    float a = bproj[t];
    for (int k = 0; k < 512; k++) a = fmaf(smem[k], Wproj[k * 300 + t], a);
    mw[b * 300 + t] = a * ow[t];
  }
}

__global__ void k_logits(const float* __restrict__ mw, const float* __restrict__ labels,
                         const float* __restrict__ ob, float* __restrict__ logits)
{
  const int b = blockIdx.x, t = threadIdx.x;
  const int a = blockIdx.y * 256 + t;
  __shared__ float smw[300];
  for (int p = t; p < 300; p += 256) smw[p] = mw[b * 300 + p];
  __syncthreads();
  if (a < 1000) {
    float acc = ob[0];
    for (int p = 0; p < 300; p++) acc = fmaf(smw[p], labels[a * 300 + p], acc);
    logits[b * 1000 + a] = acc;
  }
}

__global__ void k_softmax_out(const float* __restrict__ logits, float* __restrict__ out)
{
  const int b = blockIdx.x, t = threadIdx.x;
  __shared__ float red[256];
  float v[4]; float vmax = -INFINITY;
#pragma unroll
  for (int q = 0; q < 4; q++) {
    int a = t + q * 256;
    v[q] = (a < 1000) ? logits[b * 1000 + a] : -INFINITY;
    vmax = fmaxf(vmax, v[q]);
  }
  red[t] = vmax; __syncthreads();
  for (int s = 128; s > 0; s >>= 1) { if (t < s) red[t] = fmaxf(red[t], red[t + s]); __syncthreads(); }
  float mx = red[0]; __syncthreads();
  float lsum = 0.f;
#pragma unroll
  for (int q = 0; q < 4; q++) {
    int a = t + q * 256;
    v[q] = (a < 1000) ? expf(v[q] - mx) : 0.f;
    lsum += v[q];
  }
  red[t] = lsum; __syncthreads();
  for (int s = 128; s > 0; s >>= 1) { if (t < s) red[t] += red[t + s]; __syncthreads(); }
  float inv = 1.f / red[0];
#pragma unroll
  for (int q = 0; q < 4; q++) {
    int a = t + q * 256;
    if (a < 1000) out[b * 1000 + a] = v[q] * inv;
  }
}

// ---------------------------------------------------------------------------
extern "C" void kernel_launch(void* const* d_in, const int* in_sizes, int n_in,
                              void* d_out, int out_size, void* d_ws, size_t ws_size,
                              hipStream_t stream)
{
  const float* image    = (const float*)d_in[0];
  const float* concepts = (const float*)d_in[1];
  const float* conv1_w  = (const float*)d_in[2];
  const float* conv1_b  = (const float*)d_in[3];
  const float* conv2_w  = (const float*)d_in[4];
  const float* conv2_b  = (const float*)d_in[5];
  const float* Wci      = (const float*)d_in[6];
  const float* bci      = (const float*)d_in[7];
  const float* Wu       = (const float*)d_in[8];
  const float* bu       = (const float*)d_in[9];
  const float* caw      = (const float*)d_in[10];
  const float* cab      = (const float*)d_in[11];
  const float* Wk       = (const float*)d_in[12];
  const float* bk       = (const float*)d_in[13];
  const float* Wm       = (const float*)d_in[14];
  const float* bm       = (const float*)d_in[15];
  const float* Wcat     = (const float*)d_in[16];
  const float* bcat     = (const float*)d_in[17];
  const float* Wcat2    = (const float*)d_in[18];
  const float* bcat2    = (const float*)d_in[19];
  const float* raw      = (const float*)d_in[20];
  const float* rab      = (const float*)d_in[21];
  const float* Wwrite   = (const float*)d_in[22];
  const float* bwrite   = (const float*)d_in[23];
  const float* initc    = (const float*)d_in[24];
  const float* initm    = (const float*)d_in[25];
  const float* Wproj    = (const float*)d_in[26];
  const float* bproj    = (const float*)d_in[27];
  const float* oaw      = (const float*)d_in[28];
  const float* oab      = (const float*)d_in[29];
  const float* labels   = (const float*)d_in[30];

  char* ws = (char*)d_ws;
  // --- hand-laid workspace (aliased regions; ~151.7 MB total) ---
  const size_t OFF_KNOW = 0;                         // 51,380,224 B
  const size_t OFF_XPAD = 51380224;                  // 83,886,592 B region
  const size_t OFF_W    = 135266816;                 // 14,155,776 B region
  const size_t OFF_WKT  = 149422592;
  const size_t OFF_WC2T = 149946880;
  size_t off = 150471168;
  auto allocB = [&](size_t bytes) {
    void* p = ws + off; off += (bytes + 255) & ~(size_t)255; return p;
  };
  ushort* know   = (ushort*)(ws + OFF_KNOW);
  ushort* imgpad = (ushort*)(ws + OFF_KNOW);                 // t1-t2 only
  ushort* xpad1  = (ushort*)(ws + OFF_XPAD);                 // t1-t3 only
  ushort* kproj  = (ushort*)(ws + OFF_XPAD);                 // t4+
  ushort* befft  = (ushort*)(ws + OFF_XPAD + 51380224);      // loop
  float*  rlpart = (float*) (ws + OFF_XPAD + 55574528);      // loop
  ushort* w1b    = (ushort*)(ws + OFF_W);                    // until conv1
  ushort* w2b    = (ushort*)(ws + OFF_W);                    // until conv2
  ushort* inter1 = (ushort*)(ws + OFF_W);                    // loop
  ushort* wkt    = (ushort*)(ws + OFF_WKT);
  ushort* wc2t   = (ushort*)(ws + OFF_WC2T);
  float* rattn  = (float*)allocB((size_t)BATCH * SP * 4);
  float* ipart  = (float*)allocB((size_t)BATCH * 8 * DM * 4);
  float* cbuf   = (float*)allocB(BATCH * DM * 4);
  float* mbufA  = (float*)allocB(BATCH * DM * 4);
  float* mbufB  = (float*)allocB(BATCH * DM * 4);
  float* mp     = (float*)allocB(BATCH * DM * 4);
  float* mw     = (float*)allocB(BATCH * 300 * 4);
  float* logits = (float*)allocB(BATCH * 1000 * 4);
  if (off > ws_size) return;  // graceful fail (clean absmax mismatch)

  // --- stem ---
  k_zero<<<4096, 256, 0, stream>>>((uint4*)imgpad, 2621472L);  // 41,943,552 B
  k_zero<<<4096, 256, 0, stream>>>((uint4*)xpad1, 5242912L);   // 83,886,592 B
  k_padimg<<<50176, 256, 0, stream>>>(image, imgpad);
  k_cvtw<256><<<13824, 256, 0, stream>>>(conv1_w, w1b);
  k_cvtT<<<1024, 256, 0, stream>>>(Wk, wkt);
  k_cvtT<<<1024, 256, 0, stream>>>(Wcat2, wc2t);
  k_convm<256, 1><<<dim3(16, 4, 32), 256, 0, stream>>>(w1b, imgpad, conv1_b, xpad1);
  k_cvtw<512><<<27648, 256, 0, stream>>>(conv2_w, w2b);
  k_convm<512, 0><<<dim3(16, 4, 32), 256, 0, stream>>>(w2b, xpad1, conv2_b, know);
  k_gemmm<0><<<dim3(13, 4, 32), 256, 0, stream>>>(know, wkt, bk, nullptr, nullptr, kproj, 0);
  k_init<<<BATCH, DM, 0, stream>>>(initc, initm, cbuf, mbufA);

  float* mc = mbufA; float* mn = mbufB;
  for (int i = 0; i < NSTEP; i++) {
    k_ctrl<<<BATCH, 256, 0, stream>>>(cbuf, mc, Wci, bci,
                                      Wu + (size_t)i * DM * DM, bu + i * DM,
                                      caw, cab, concepts, Wm, bm, cbuf, mp);
    for (int g = 0; g < 4; g++) {
      int bbase = g * 8;
      k_prefold<<<dim3(8, 8), 256, 0, stream>>>(Wcat, mp, befft, bbase);
      k_gemmm<1><<<dim3(13, 4, 8), 256, 0, stream>>>(
          kproj + (size_t)bbase * SP * DM, befft, bcat, nullptr, nullptr, inter1, bbase);
      k_gemmm<2><<<dim3(13, 4, 8), 256, 0, stream>>>(
          inter1, wc2t, bcat2, cbuf, raw, rlpart, bbase);
    }
    k_softmax_read<<<BATCH, 256, 0, stream>>>(rlpart, rab, rattn);
    k_infopart<<<dim3(BATCH, 8), 256, 0, stream>>>(rattn, know, ipart);
    k_write<<<dim3(BATCH, 2), 256, 0, stream>>>(mc, ipart, Wwrite, bwrite, mn);
    float* tswap = mc; mc = mn; mn = tswap;
  }

  k_mpo<<<BATCH, 320, 0, stream>>>(mc, Wproj, bproj, oaw, mw);
  k_logits<<<dim3(BATCH, 4), 256, 0, stream>>>(mw, labels, oab, logits);
  k_softmax_out<<<BATCH, 256, 0, stream>>>(logits, (float*)d_out);

  (void)in_sizes; (void)n_in; (void)out_size;
}

// Round 4
// 8172.762 us; speedup vs baseline: 3.9926x; 1.1636x over previous
//
#include <hip/hip_runtime.h>
#include <math.h>

#define DM    512
#define SP    1568   // 8*14*14
#define BATCH 32
#define NSTEP 12
#define CPAD  2560   // padded per-batch spatial rows (10*16*16)
#define LDT   40     // LDS tile row stride (bf16 elems)

typedef short s16x8 __attribute__((ext_vector_type(8)));
typedef float f32x4 __attribute__((ext_vector_type(4)));

__device__ __forceinline__ float eluf(float x) { return x > 0.f ? x : expf(x) - 1.f; }
__device__ __forceinline__ float b2f(ushort u) {
  union { float f; unsigned i; } v; v.i = ((unsigned)u) << 16; return v.f;
}
__device__ __forceinline__ ushort f2b(float f) {
  union { float f; unsigned i; } v; v.f = f;
  unsigned r = (v.i + 0x7FFFu + ((v.i >> 16) & 1u)) >> 16;
  return (ushort)r;
}

// ---------------------------------------------------------------------------
__global__ void k_zero(uint4* __restrict__ p, long n16) {
  long stride = (long)gridDim.x * blockDim.x;
  for (long i = (long)blockIdx.x * blockDim.x + threadIdx.x; i < n16; i += stride)
    p[i] = make_uint4(0, 0, 0, 0);
}

// image [32][256][1568] fp32 -> NHWC padded bf16 [b][2560][256] (interior only)
__global__ void k_padimg(const float* __restrict__ img, ushort* __restrict__ xp) {
  int blk = blockIdx.x;                 // 32*1568
  int b = blk / SP, s = blk - b * SP;
  int ci = threadIdx.x;                 // 256
  int z = s / 196, r = s - z * 196, y = r / 14, x = r - y * 14;
  int p = (z + 1) * 256 + (y + 1) * 16 + (x + 1);
  xp[((size_t)b * CPAD + p) * 256 + ci] = f2b(img[((size_t)b * 256 + ci) * SP + s]);
}

// conv weights [co][ci][27] fp32 -> tap-major bf16 [co][tap*CIN+ci]
template <int CIN>
__global__ void k_cvtw(const float* __restrict__ w, ushort* __restrict__ o) {
  int idx = blockIdx.x * 256 + threadIdx.x;   // < 512*27*CIN
  const int KK = 27 * CIN;
  int co = idx / KK; int rem = idx - co * KK;
  int tap = rem / CIN; int ci = rem - tap * CIN;
  o[idx] = f2b(w[((size_t)co * CIN + ci) * 27 + tap]);
}

// [512][512] fp32 -> transposed bf16 [n][k]
__global__ void k_cvtT(const float* __restrict__ w, ushort* __restrict__ o) {
  int idx = blockIdx.x * 256 + threadIdx.x;   // < 512*512
  int n = idx >> 9, k = idx & 511;
  o[idx] = f2b(w[(size_t)k * 512 + n]);
}

// ---------------------------------------------------------------------------
// MFMA conv3d, NHWC activations: implicit GEMM, M=co(512), N=s_pad(2048),
// K=27*CIN tap-major. B tile per K-chunk = 128 spatial rows x 32 contiguous
// channels of one tap -> coalesced uint4 loads, b128 LDS writes.
// ISCONV1: store NHWC-padded (+ELU+bias); else store know [b][s][d].
// ---------------------------------------------------------------------------
template <int CIN, int ISCONV1>
__global__ __launch_bounds__(256) void k_convm(
    const ushort* __restrict__ W, const ushort* __restrict__ Xp,
    const float* __restrict__ bias, ushort* __restrict__ Y)
{
  const int KK = CIN * 27;
  const int b  = blockIdx.z;
  const int n0 = blockIdx.x * 128;
  const int m0 = blockIdx.y * 128;
  __shared__ __align__(16) ushort As[128 * LDT];
  __shared__ __align__(16) ushort Bs[128 * LDT];
  const int t = threadIdx.x;
  const int lane = t & 63, wid = t >> 6;
  const int wm = (wid >> 1) * 64, wn = (wid & 1) * 64;
  const int l15 = lane & 15, quad = lane >> 4;
  f32x4 acc[4][4];
#pragma unroll
  for (int i = 0; i < 4; i++)
#pragma unroll
    for (int j = 0; j < 4; j++) acc[i][j] = (f32x4){0.f, 0.f, 0.f, 0.f};

  const int nn = t >> 2, q = t & 3;
  for (int k0 = 0; k0 < KK; k0 += 32) {
#pragma unroll
    for (int i = 0; i < 2; i++) {          // A tile: 128co x 32k, b128
      int f = t + i * 256;
      int row = f >> 2, ko = (f & 3) * 8;
      uint4 v = *(const uint4*)&W[(size_t)(m0 + row) * KK + k0 + ko];
      *(uint4*)&As[row * LDT + ko] = v;
    }
    {                                       // B tile: fixed tap, NHWC
      int tap = k0 / CIN, ci0 = k0 - tap * CIN;
      int dz = tap / 9, rr = tap - dz * 9, dy = rr / 3, dx = rr - dy * 3;
      int tofs = dz * 256 + dy * 16 + dx;
      const ushort* src = Xp + ((size_t)b * CPAD + tofs + n0) * CIN + ci0;
#pragma unroll
      for (int h = 0; h < 2; h++) {
        int row = nn + h * 64;
        uint4 v = *(const uint4*)&src[(size_t)row * CIN + q * 8];
        *(uint4*)&Bs[row * LDT + q * 8] = v;
      }
    }
    __syncthreads();
    s16x8 af[4], bfr[4];
#pragma unroll
    for (int i = 0; i < 4; i++)
      af[i] = *(const s16x8*)&As[(wm + i * 16 + l15) * LDT + quad * 8];
#pragma unroll
    for (int j = 0; j < 4; j++)
      bfr[j] = *(const s16x8*)&Bs[(wn + j * 16 + l15) * LDT + quad * 8];
#pragma unroll
    for (int i = 0; i < 4; i++)
#pragma unroll
      for (int j = 0; j < 4; j++)
        acc[i][j] = __builtin_amdgcn_mfma_f32_16x16x32_bf16(af[i], bfr[j], acc[i][j], 0, 0, 0);
    __syncthreads();
  }

#pragma unroll
  for (int i = 0; i < 4; i++) {
    int cob = m0 + wm + i * 16 + quad * 4;
    float4 bb = *(const float4*)&bias[cob];
#pragma unroll
    for (int j = 0; j < 4; j++) {
      int n = n0 + wn + j * 16 + l15;
      int z = n >> 8, y = (n >> 4) & 15, x = n & 15;
      if (y < 14 && x < 14) {
        ushort4 o;
        o.x = f2b(eluf(acc[i][j][0] + bb.x));
        o.y = f2b(eluf(acc[i][j][1] + bb.y));
        o.z = f2b(eluf(acc[i][j][2] + bb.z));
        o.w = f2b(eluf(acc[i][j][3] + bb.w));
        if (ISCONV1) {
          *(ushort4*)&Y[((size_t)b * CPAD + n + 273) * 512 + cob] = o;  // NHWC pad
        } else {
          int s = z * 196 + y * 14 + x;
          *(ushort4*)&Y[((size_t)b * SP + s) * DM + cob] = o;           // know
        }
      }
    }
  }
}

// ---------------------------------------------------------------------------
// MFMA GEMM: M = s (1568, masked), N = 512, K = 512. A bf16 [s][k], Bt bf16 [n][k].
// MODE 0: kproj = A@B + bias                 -> bf16
// MODE 1: inter1 = elu(A@Beff[bq] + bias)    -> bf16
// MODE 2: rlpart = sum_n elu((A@B+bias)*c)*raw  -> fp32, per n-tile
// ---------------------------------------------------------------------------
template <int MODE>
__global__ __launch_bounds__(256) void k_gemmm(
    const ushort* __restrict__ A0, const ushort* __restrict__ Bt0,
    const float* __restrict__ bias, const float* __restrict__ scale,
    const float* __restrict__ rvec, void* __restrict__ Cv, int bbase)
{
  const int bq = blockIdx.z, breal = bbase + bq;
  const int m0 = blockIdx.x * 128;
  const int n0 = blockIdx.y * 128;
  const ushort* A  = A0 + (size_t)bq * SP * DM;
  const ushort* Bt = (MODE == 1) ? Bt0 + (size_t)bq * DM * DM : Bt0;
  __shared__ __align__(16) ushort As[128 * LDT];
  __shared__ __align__(16) ushort Bs[128 * LDT];
  const int t = threadIdx.x;
  const int lane = t & 63, wid = t >> 6;
  const int wm = (wid >> 1) * 64, wn = (wid & 1) * 64;
  const int l15 = lane & 15, quad = lane >> 4;
  f32x4 acc[4][4];
#pragma unroll
  for (int i = 0; i < 4; i++)
#pragma unroll
    for (int j = 0; j < 4; j++) acc[i][j] = (f32x4){0.f, 0.f, 0.f, 0.f};

  for (int k0 = 0; k0 < DM; k0 += 32) {
#pragma unroll
    for (int i = 0; i < 2; i++) {
      int f = t + i * 256;
      int row = f >> 2, ko = (f & 3) * 8;
      int mg = m0 + row;
      uint4 v = make_uint4(0, 0, 0, 0);
      if (mg < SP) v = *(const uint4*)&A[(size_t)mg * DM + k0 + ko];
      *(uint4*)&As[row * LDT + ko] = v;
      uint4 w = *(const uint4*)&Bt[(size_t)(n0 + row) * DM + k0 + ko];
      *(uint4*)&Bs[row * LDT + ko] = w;
    }
    __syncthreads();
    s16x8 af[4], bfr[4];
#pragma unroll
    for (int i = 0; i < 4; i++)
      af[i] = *(const s16x8*)&As[(wm + i * 16 + l15) * LDT + quad * 8];
#pragma unroll
    for (int j = 0; j < 4; j++)
      bfr[j] = *(const s16x8*)&Bs[(wn + j * 16 + l15) * LDT + quad * 8];
#pragma unroll
    for (int i = 0; i < 4; i++)
#pragma unroll
      for (int j = 0; j < 4; j++)
        acc[i][j] = __builtin_amdgcn_mfma_f32_16x16x32_bf16(af[i], bfr[j], acc[i][j], 0, 0, 0);
    __syncthreads();
  }

  if constexpr (MODE <= 1) {
    ushort* C = (ushort*)Cv + (size_t)bq * SP * DM;
#pragma unroll
    for (int j = 0; j < 4; j++) {
      int n = n0 + wn + j * 16 + l15;
      float bb = bias[n];
#pragma unroll
      for (int i = 0; i < 4; i++) {
        int mb = m0 + wm + i * 16 + quad * 4;
#pragma unroll
        for (int r = 0; r < 4; r++) {
          int m = mb + r;
          if (m < SP) {
            float v = acc[i][j][r] + bb;
            if (MODE == 1) v = eluf(v);
            C[(size_t)m * DM + n] = f2b(v);
          }
        }
      }
    }
  } else {
    __shared__ float red[128][33];
    float* C = (float*)Cv;
#pragma unroll
    for (int i = 0; i < 4; i++) {
#pragma unroll
      for (int r = 0; r < 4; r++) {
        float p = 0.f;
#pragma unroll
        for (int j = 0; j < 4; j++) {
          int n = n0 + wn + j * 16 + l15;
          p += eluf((acc[i][j][r] + bias[n]) * scale[(size_t)breal * DM + n]) * rvec[n];
        }
        red[wm + i * 16 + quad * 4 + r][(wid & 1) * 16 + l15] = p;
      }
    }
    __syncthreads();
    if (t < 128) {
      int m = m0 + t;
      float s = 0.f;
#pragma unroll
      for (int q = 0; q < 32; q++) s += red[t][q];
      if (m < SP) C[((size_t)breal * 4 + blockIdx.y) * SP + m] = s;
    }
  }
}

// ---------------------------------------------------------------------------
// Per-step fold: Beff_t[b][n][k] = bf16(mp[b][k]*Wcat[k][n] + Wcat[512+k][n])
// One launch covers all 32 batches (grid z = 4 groups of 8).
// ---------------------------------------------------------------------------
__global__ __launch_bounds__(256) void k_prefold(
    const float* __restrict__ Wcat, const float* __restrict__ mp,
    ushort* __restrict__ Bf)
{
  const int k0 = blockIdx.x * 64, n0 = blockIdx.y * 64;
  const int bbase = blockIdx.z * 8;
  __shared__ float S1[64][68], S2[64][68];
  const int t = threadIdx.x;
#pragma unroll
  for (int i = 0; i < 4; i++) {
    int f = t + i * 256;
    int kk = f >> 4, nn2 = (f & 15) * 4;
    float4 a = *(const float4*)&Wcat[(size_t)(k0 + kk) * DM + n0 + nn2];
    float4 c = *(const float4*)&Wcat[(size_t)(DM + k0 + kk) * DM + n0 + nn2];
    *(float4*)&S1[kk][nn2] = a;
    *(float4*)&S2[kk][nn2] = c;
  }
  __syncthreads();
  const int n = t >> 2, kseg = (t & 3) * 16;
  for (int bq = 0; bq < 8; bq++) {
    const float* mpb = mp + (size_t)(bbase + bq) * DM + k0 + kseg;
    ushort* out = Bf + ((size_t)(bbase + bq) * DM + n0 + n) * DM + k0 + kseg;
#pragma unroll
    for (int g = 0; g < 4; g++) {
      ushort4 o;
      o.x = f2b(mpb[g * 4 + 0] * S1[kseg + g * 4 + 0][n] + S2[kseg + g * 4 + 0][n]);
      o.y = f2b(mpb[g * 4 + 1] * S1[kseg + g * 4 + 1][n] + S2[kseg + g * 4 + 1][n]);
      o.z = f2b(mpb[g * 4 + 2] * S1[kseg + g * 4 + 2][n] + S2[kseg + g * 4 + 2][n]);
      o.w = f2b(mpb[g * 4 + 3] * S1[kseg + g * 4 + 3][n] + S2[kseg + g * 4 + 3][n]);
      *(ushort4*)&out[g * 4] = o;
    }
  }
}

// ---------------------------------------------------------------------------
// Small fused per-step kernels (fp32)
// ---------------------------------------------------------------------------
__global__ __launch_bounds__(256) void k_ctrl(
    const float* cin, const float* __restrict__ min_,
    const float* __restrict__ Wci, const float* __restrict__ bci,
    const float* __restrict__ Wu_i, const float* __restrict__ bu_i,
    const float* __restrict__ caw, const float* __restrict__ cab,
    const float* __restrict__ concepts,
    const float* __restrict__ Wm, const float* __restrict__ bm,
    float* cout, float* __restrict__ mpout)
{
  const int b = blockIdx.x, t = threadIdx.x;
  __shared__ float sc[512], sm[512], sq0[512], sqa[512], scl[80], red[256];
  sc[t] = cin[b * DM + t];       sc[t + 256] = cin[b * DM + t + 256];
  sm[t] = min_[b * DM + t];      sm[t + 256] = min_[b * DM + t + 256];
  __syncthreads();
#pragma unroll
  for (int h = 0; h < 2; h++) {
    int d = t + h * 256;
    float a = bci[d];
    for (int k = 0; k < 512; k++) a = fmaf(sc[k], Wci[k * DM + d], a);
    for (int k = 0; k < 512; k++) a = fmaf(sm[k], Wci[(512 + k) * DM + d], a);
    sq0[d] = tanhf(a);
    float mpa = bm[d];
    for (int k = 0; k < 512; k++) mpa = fmaf(sm[k], Wm[k * DM + d], mpa);
    mpout[b * DM + d] = mpa;
  }
  __syncthreads();
#pragma unroll
  for (int h = 0; h < 2; h++) {
    int d = t + h * 256;
    float a = bu_i[d];
    for (int k = 0; k < 512; k++) a = fmaf(sq0[k], Wu_i[k * DM + d], a);
    sqa[d] = a * caw[d];
  }
  __syncthreads();
  float myl = -INFINITY;
  if (t < 80) {
    float a = cab[0];
    for (int d = 0; d < 512; d++) a = fmaf(sqa[d], concepts[t * DM + d], a);
    scl[t] = a; myl = a;
  }
  red[t] = myl; __syncthreads();
  for (int s = 128; s > 0; s >>= 1) { if (t < s) red[t] = fmaxf(red[t], red[t + s]); __syncthreads(); }
  float mx = red[0]; __syncthreads();
  float e = 0.f;
  if (t < 80) e = expf(scl[t] - mx);
  red[t] = e; __syncthreads();
  for (int s = 128; s > 0; s >>= 1) { if (t < s) red[t] += red[t + s]; __syncthreads(); }
  float inv = 1.f / red[0]; __syncthreads();
  if (t < 80) scl[t] = e * inv;
  __syncthreads();
#pragma unroll
  for (int h = 0; h < 2; h++) {
    int d = t + h * 256;
    float a = 0.f;
    for (int l = 0; l < 80; l++) a = fmaf(scl[l], concepts[l * DM + d], a);
    cout[b * DM + d] = a;
  }
}

__global__ __launch_bounds__(256) void k_softmax_read(
    const float* __restrict__ rlpart, const float* __restrict__ rb,
    float* __restrict__ rattn)
{
  const int b = blockIdx.x, t = threadIdx.x;
  __shared__ float red[256];
  const float rb0 = rb[0];
  float vals[7]; float vmax = -INFINITY;
#pragma unroll
  for (int q = 0; q < 7; q++) {
    int s = t + q * 256;
    float v = -INFINITY;
    if (s < SP) {
      v = rb0;
      for (int c = 0; c < 4; c++) v += rlpart[((size_t)b * 4 + c) * SP + s];
    }
    vals[q] = v; vmax = fmaxf(vmax, v);
  }
  red[t] = vmax; __syncthreads();
  for (int s = 128; s > 0; s >>= 1) { if (t < s) red[t] = fmaxf(red[t], red[t + s]); __syncthreads(); }
  float mx = red[0]; __syncthreads();
  float lsum = 0.f;
#pragma unroll
  for (int q = 0; q < 7; q++) {
    int s = t + q * 256;
    float ee = (s < SP) ? expf(vals[q] - mx) : 0.f;
    vals[q] = ee; lsum += ee;
  }
  red[t] = lsum; __syncthreads();
  for (int s = 128; s > 0; s >>= 1) { if (t < s) red[t] += red[t + s]; __syncthreads(); }
  float inv = 1.f / red[0];
#pragma unroll
  for (int q = 0; q < 7; q++) {
    int s = t + q * 256;
    if (s < SP) rattn[b * SP + s] = vals[q] * inv;
  }
}

__global__ __launch_bounds__(256) void k_infopart(
    const float* __restrict__ rattn, const ushort* __restrict__ know,
    float* __restrict__ ipart)
{
  const int b = blockIdx.x, c = blockIdx.y, t = threadIdx.x;
  float a0 = 0.f, a1 = 0.f;
  for (int s = c * 196; s < (c + 1) * 196; s++) {
    float r = rattn[b * SP + s];
    const ushort* kr = know + ((size_t)b * SP + s) * DM;
    a0 = fmaf(r, b2f(kr[t]), a0);
    a1 = fmaf(r, b2f(kr[t + 256]), a1);
  }
  ipart[((size_t)b * 8 + c) * DM + t] = a0;
  ipart[((size_t)b * 8 + c) * DM + t + 256] = a1;
}

__global__ __launch_bounds__(256) void k_write(
    const float* __restrict__ mold, const float* __restrict__ ipart,
    const float* __restrict__ Ww, const float* __restrict__ bw,
    float* __restrict__ mnew)
{
  const int b = blockIdx.x, half = blockIdx.y, t = threadIdx.x;
  __shared__ float smo[512], sinfo[512];
  for (int k = t; k < 512; k += 256) {
    smo[k] = mold[b * DM + k];
    float s = 0.f;
    for (int c = 0; c < 8; c++) s += ipart[((size_t)b * 8 + c) * DM + k];
    sinfo[k] = s;
  }
  __syncthreads();
  int d = half * 256 + t;
  float a = bw[d];
  for (int k = 0; k < 512; k++) a = fmaf(smo[k], Ww[k * DM + d], a);
  for (int k = 0; k < 512; k++) a = fmaf(sinfo[k], Ww[(512 + k) * DM + d], a);
  mnew[b * DM + d] = a;
}

__global__ void k_init(const float* __restrict__ initc, const float* __restrict__ initm,
                       float* __restrict__ cbuf, float* __restrict__ mbuf)
{
  const int b = blockIdx.x, t = threadIdx.x;
  cbuf[b * DM + t] = initc[t];
  mbuf[b * DM + t] = initm[t];
}

__global__ void k_mpo(const float* __restrict__ m, const float* __restrict__ Wproj,
                      const float* __restrict__ bproj, const float* __restrict__ ow,
                      float* __restrict__ mw)
{
  const int b = blockIdx.x, t = threadIdx.x;
  __shared__ float smem[512];
  for (int k = t; k < 512; k += 320) smem[k] = m[b * DM + k];
  __syncthreads();
  if (t < 300) {
    float a = bproj[t];
    for (int k = 0; k < 512; k++) a = fmaf(smem[k], Wproj[k * 300 + t], a);
    mw[b * 300 + t] = a * ow[t];
  }
}

__global__ void k_logits(const float* __restrict__ mw, const float* __restrict__ labels,
                         const float* __restrict__ ob, float* __restrict__ logits)
{
  const int b = blockIdx.x, t = threadIdx.x;
  const int a = blockIdx.y * 256 + t;
  __shared__ float smw[300];
  for (int p = t; p < 300; p += 256) smw[p] = mw[b * 300 + p];
  __syncthreads();
  if (a < 1000) {
    float acc = ob[0];
    for (int p = 0; p < 300; p++) acc = fmaf(smw[p], labels[a * 300 + p], acc);
    logits[b * 1000 + a] = acc;
  }
}

__global__ void k_softmax_out(const float* __restrict__ logits, float* __restrict__ out)
{
  const int b = blockIdx.x, t = threadIdx.x;
  __shared__ float red[256];
  float v[4]; float vmax = -INFINITY;
#pragma unroll
  for (int q = 0; q < 4; q++) {
    int a = t + q * 256;
    v[q] = (a < 1000) ? logits[b * 1000 + a] : -INFINITY;
    vmax = fmaxf(vmax, v[q]);
  }
  red[t] = vmax; __syncthreads();
  for (int s = 128; s > 0; s >>= 1) { if (t < s) red[t] = fmaxf(red[t], red[t + s]); __syncthreads(); }
  float mx = red[0]; __syncthreads();
  float lsum = 0.f;
#pragma unroll
  for (int q = 0; q < 4; q++) {
    int a = t + q * 256;
    v[q] = (a < 1000) ? expf(v[q] - mx) : 0.f;
    lsum += v[q];
  }
  red[t] = lsum; __syncthreads();
  for (int s = 128; s > 0; s >>= 1) { if (t < s) red[t] += red[t + s]; __syncthreads(); }
  float inv = 1.f / red[0];
#pragma unroll
  for (int q = 0; q < 4; q++) {
    int a = t + q * 256;
    if (a < 1000) out[b * 1000 + a] = v[q] * inv;
  }
}

// ---------------------------------------------------------------------------
extern "C" void kernel_launch(void* const* d_in, const int* in_sizes, int n_in,
                              void* d_out, int out_size, void* d_ws, size_t ws_size,
                              hipStream_t stream)
{
  const float* image    = (const float*)d_in[0];
  const float* concepts = (const float*)d_in[1];
  const float* conv1_w  = (const float*)d_in[2];
  const float* conv1_b  = (const float*)d_in[3];
  const float* conv2_w  = (const float*)d_in[4];
  const float* conv2_b  = (const float*)d_in[5];
  const float* Wci      = (const float*)d_in[6];
  const float* bci      = (const float*)d_in[7];
  const float* Wu       = (const float*)d_in[8];
  const float* bu       = (const float*)d_in[9];
  const float* caw      = (const float*)d_in[10];
  const float* cab      = (const float*)d_in[11];
  const float* Wk       = (const float*)d_in[12];
  const float* bk       = (const float*)d_in[13];
  const float* Wm       = (const float*)d_in[14];
  const float* bm       = (const float*)d_in[15];
  const float* Wcat     = (const float*)d_in[16];
  const float* bcat     = (const float*)d_in[17];
  const float* Wcat2    = (const float*)d_in[18];
  const float* bcat2    = (const float*)d_in[19];
  const float* raw      = (const float*)d_in[20];
  const float* rab      = (const float*)d_in[21];
  const float* Wwrite   = (const float*)d_in[22];
  const float* bwrite   = (const float*)d_in[23];
  const float* initc    = (const float*)d_in[24];
  const float* initm    = (const float*)d_in[25];
  const float* Wproj    = (const float*)d_in[26];
  const float* bproj    = (const float*)d_in[27];
  const float* oaw      = (const float*)d_in[28];
  const float* oab      = (const float*)d_in[29];
  const float* labels   = (const float*)d_in[30];

  char* ws = (char*)d_ws;
  // --- hand-laid workspace (aliased regions; ~151.7 MB) ---
  // region1: know (51,380,224) | imgpad NHWC (41.94MB + slack) during stem
  // region2: xpad1 NHWC (83.89MB + 64K slack) -> kproj + befft + rlpart in loop
  // region3: conv weights bf16 (14.16MB) -> inter1 (12.85MB, 8 batches) in loop
  const size_t OFF_KNOW = 0;
  const size_t OFF_XPAD = 51380224;
  const size_t SZ_XPAD  = 83951616;                  // 83,886,080 + 65,536 slack
  const size_t OFF_W    = OFF_XPAD + SZ_XPAD;        // 135,331,840
  const size_t OFF_WKT  = OFF_W + 14155776;          // 149,487,616
  const size_t OFF_WC2T = OFF_WKT + 524288;          // 150,011,904
  size_t off = OFF_WC2T + 524288;                    // 150,536,192
  auto allocB = [&](size_t bytes) {
    void* p = ws + off; off += (bytes + 255) & ~(size_t)255; return p;
  };
  ushort* know   = (ushort*)(ws + OFF_KNOW);
  ushort* imgpad = (ushort*)(ws + OFF_KNOW);                 // stem only
  ushort* xpad1  = (ushort*)(ws + OFF_XPAD);                 // stem only
  ushort* kproj  = (ushort*)(ws + OFF_XPAD);                 // loop
  ushort* befft  = (ushort*)(ws + OFF_XPAD + 51380224);      // loop, 16.78MB
  float*  rlpart = (float*) (ws + OFF_XPAD + 68157440);      // loop, 0.8MB
  ushort* w1b    = (ushort*)(ws + OFF_W);
  ushort* w2b    = (ushort*)(ws + OFF_W);
  ushort* inter1 = (ushort*)(ws + OFF_W);
  ushort* wkt    = (ushort*)(ws + OFF_WKT);
  ushort* wc2t   = (ushort*)(ws + OFF_WC2T);
  float* rattn  = (float*)allocB((size_t)BATCH * SP * 4);
  float* ipart  = (float*)allocB((size_t)BATCH * 8 * DM * 4);
  float* cbuf   = (float*)allocB(BATCH * DM * 4);
  float* mbufA  = (float*)allocB(BATCH * DM * 4);
  float* mbufB  = (float*)allocB(BATCH * DM * 4);
  float* mp     = (float*)allocB(BATCH * DM * 4);
  float* mw     = (float*)allocB(BATCH * 300 * 4);
  float* logits = (float*)allocB(BATCH * 1000 * 4);
  if (off > ws_size) return;  // graceful fail

  // --- stem ---
  k_zero<<<4096, 256, 0, stream>>>((uint4*)imgpad, 2625536L);  // 42,008,576 B
  k_zero<<<4096, 256, 0, stream>>>((uint4*)xpad1, 5246976L);   // 83,951,616 B
  k_padimg<<<BATCH * SP, 256, 0, stream>>>(image, imgpad);
  k_cvtw<256><<<13824, 256, 0, stream>>>(conv1_w, w1b);
  k_cvtT<<<1024, 256, 0, stream>>>(Wk, wkt);
  k_cvtT<<<1024, 256, 0, stream>>>(Wcat2, wc2t);
  k_convm<256, 1><<<dim3(16, 4, 32), 256, 0, stream>>>(w1b, imgpad, conv1_b, xpad1);
  k_cvtw<512><<<27648, 256, 0, stream>>>(conv2_w, w2b);
  k_convm<512, 0><<<dim3(16, 4, 32), 256, 0, stream>>>(w2b, xpad1, conv2_b, know);
  k_gemmm<0><<<dim3(13, 4, 32), 256, 0, stream>>>(know, wkt, bk, nullptr, nullptr, kproj, 0);
  k_init<<<BATCH, DM, 0, stream>>>(initc, initm, cbuf, mbufA);

  float* mc = mbufA; float* mn = mbufB;
  for (int i = 0; i < NSTEP; i++) {
    k_ctrl<<<BATCH, 256, 0, stream>>>(cbuf, mc, Wci, bci,
                                      Wu + (size_t)i * DM * DM, bu + i * DM,
                                      caw, cab, concepts, Wm, bm, cbuf, mp);
    k_prefold<<<dim3(8, 8, 4), 256, 0, stream>>>(Wcat, mp, befft);
    for (int g = 0; g < 4; g++) {
      int bbase = g * 8;
      k_gemmm<1><<<dim3(13, 4, 8), 256, 0, stream>>>(
          kproj + (size_t)bbase * SP * DM, befft + (size_t)bbase * DM * DM,
          bcat, nullptr, nullptr, inter1, bbase);
      k_gemmm<2><<<dim3(13, 4, 8), 256, 0, stream>>>(
          inter1, wc2t, bcat2, cbuf, raw, rlpart, bbase);
    }
    k_softmax_read<<<BATCH, 256, 0, stream>>>(rlpart, rab, rattn);
    k_infopart<<<dim3(BATCH, 8), 256, 0, stream>>>(rattn, know, ipart);
    k_write<<<dim3(BATCH, 2), 256, 0, stream>>>(mc, ipart, Wwrite, bwrite, mn);
    float* tswap = mc; mc = mn; mn = tswap;
  }

  k_mpo<<<BATCH, 320, 0, stream>>>(mc, Wproj, bproj, oaw, mw);
  k_logits<<<dim3(BATCH, 4), 256, 0, stream>>>(mw, labels, oab, logits);
  k_softmax_out<<<BATCH, 256, 0, stream>>>(logits, (float*)d_out);

  (void)in_sizes; (void)n_in; (void)out_size;
}